// Round 10
// baseline (227.312 us; speedup 1.0000x reference)
//
#include <hip/hip_runtime.h>
#include <hip/hip_fp16.h>

// PosteriorHiddenTreeMarkovModel — MI355X / gfx950
// R10: 2 waves per subtree (split by NODE: wave h handles nodes (n<<1)|h per
// level, full 8-state work per node). 864 blocks x 256 thr = 3456 waves =
// 13.5 waves/CU (R9 had 432 blocks / 6.75 waves/CU — block count, not LDS cap,
// was the occupancy limiter). Per-level ordering via block __syncthreads.
// Deadlock-safety: all 864 blocks must be co-resident -> 4 blocks/CU ->
// LDS <= 40960B (achieved: 2 subtrees/block, bMid beta in fp16, s fp32;
// ~39.4KB) and VGPR <= 128 (__launch_bounds__(256,4)).
// Sync: per-tree counters (27 h0-posts) + per-tree flags, relaxed agent-scope
// polls (no fence storms — R8/R9 lesson); one __threadfence per block after
// the Bm gate. Mid phase (q==0,h==0 wave) uses wave barriers only.

namespace {

constexpr int kNPT = 3280;
constexpr int kRS  = 72;   // subtree record stride: 64 beta + 8 pre-norm sums
constexpr unsigned kMAGIC  = 0x13579BDFu;
constexpr unsigned kMAGIC2 = 0x2468ACEFu;
__device__ __constant__ int LO[6] = {0, 1, 4, 13, 40, 121};
__device__ __constant__ int P3[5] = {1, 3, 9, 27, 81};

#define AGENT_LD(p)    __hip_atomic_load((p), __ATOMIC_RELAXED, __HIP_MEMORY_SCOPE_AGENT)
#define AGENT_ST(p, v) __hip_atomic_store((p), (v), __ATOMIC_RELAXED, __HIP_MEMORY_SCOPE_AGENT)

__device__ __forceinline__ void leaf_beta(const float* __restrict__ sPi,
                                          const float* __restrict__ pBm,
                                          int p, int xv, int g, float* b)
{
    float s = 0.f;
    #pragma unroll
    for (int c = 0; c < 8; ++c) {
        b[c] = sPi[(c * 3 + p) * 8 + g] * pBm[xv * 64 + c * 8 + g];
        s += b[c];
    }
    float ig = __builtin_amdgcn_rcpf(s);
    #pragma unroll
    for (int c = 0; c < 8; ++c) b[c] *= ig;
}

__global__ __launch_bounds__(256, 4)
void fused(const float* __restrict__ lamA, const float* __restrict__ lamB,
           const float* __restrict__ lamPi, const float* __restrict__ lamSP,
           const int* __restrict__ x, float* __restrict__ out,
           unsigned* __restrict__ sy, float* __restrict__ bmG,
           float* __restrict__ b3, float* __restrict__ e3)
{
    const int tid = threadIdx.x, w = tid >> 6, lane = tid & 63;
    const int n = lane >> 3, g = lane & 7;
    const int sub = w >> 1, h = w & 1;
    __shared__ float sA[1536], sALA[1536], sPi[192], sLPi[192], sSP[24], sLSP[24];
    __shared__ float bW[2][40 * kRS];      // per-subtree records (fp32)
    __shared__ __half bMidH[13 * 64];      // mid beta records, fp16, stride 64
    __shared__ float sMs[13 * 8];          // mid pre-norm sums, fp32
    __shared__ unsigned char xW[2][124];
    unsigned* trCnt = sy + 32;
    unsigned* trFlg = sy + 2080;

    // ---- init gate ----
    if (tid == 0) {
        if (blockIdx.x == 0) {
            for (int i = 0; i < 64; ++i) AGENT_ST(&trCnt[i * 32], 0u);
            __builtin_amdgcn_s_waitcnt(0);
            AGENT_ST(&sy[0], kMAGIC);
        }
        unsigned long sp = 0;
        while (AGENT_LD(&sy[0]) != kMAGIC) {
            if (++sp > (1UL << 24)) break;
            __builtin_amdgcn_s_sleep(2);
        }
    }
    __syncthreads();

    // ================= phase 0: parameters =================
    if (blockIdx.x == 0) {   // Bm softmax -> bmG (transposed [m][c][g]) + flag
        float* rr = &bW[0][0];
        int row = tid >> 2, part = tid & 3;
        int c = row >> 3, gg = row & 7, m0 = part * 32;
        float mx = -1e30f;
        for (int mm = 0; mm < 32; ++mm)
            mx = fmaxf(mx, lamB[(c * 128 + m0 + mm) * 8 + gg]);
        rr[tid] = mx;
        __syncthreads();
        float m4 = fmaxf(fmaxf(rr[row * 4], rr[row * 4 + 1]),
                         fmaxf(rr[row * 4 + 2], rr[row * 4 + 3]));
        float s = 0.f;
        for (int mm = 0; mm < 32; ++mm)
            s += expf(lamB[(c * 128 + m0 + mm) * 8 + gg] - m4);
        rr[256 + tid] = s;
        __syncthreads();
        float stot = rr[256 + row * 4] + rr[256 + row * 4 + 1]
                   + rr[256 + row * 4 + 2] + rr[256 + row * 4 + 3];
        float inv = 1.f / stot;
        for (int mm = 0; mm < 32; ++mm)
            AGENT_ST(&bmG[(m0 + mm) * 64 + c * 8 + gg],
                     expf(lamB[(c * 128 + m0 + mm) * 8 + gg] - m4) * inv);
        __syncthreads();
        if (tid == 0) AGENT_ST(&sy[4], kMAGIC2);
    }
    for (int col = tid; col < 192; col += 256) {          // A softmax over i
        int j = col / 24; int rem = col - j * 24; int p = rem >> 3; int gg = rem & 7;
        float v[8]; float mx = -1e30f;
        #pragma unroll
        for (int i = 0; i < 8; ++i) {
            v[i] = lamA[((i * 8 + j) * 3 + p) * 8 + gg];
            mx = fmaxf(mx, v[i]);
        }
        float s = 0.f;
        #pragma unroll
        for (int i = 0; i < 8; ++i) { v[i] = expf(v[i] - mx); s += v[i]; }
        float inv = 1.f / s;
        #pragma unroll
        for (int i = 0; i < 8; ++i) {
            int idx = ((i * 8 + j) * 3 + p) * 8 + gg;
            float sm = v[i] * inv;
            sA[idx]   = sm;
            sALA[idx] = sm * logf(sm);
        }
    }
    for (int col = tid; col < 24; col += 256) {           // Pi softmax over c
        int p = col >> 3; int gg = col & 7;
        float v[8]; float mx = -1e30f;
        #pragma unroll
        for (int c = 0; c < 8; ++c) {
            v[c] = lamPi[(c * 3 + p) * 8 + gg];
            mx = fmaxf(mx, v[c]);
        }
        float s = 0.f;
        #pragma unroll
        for (int c = 0; c < 8; ++c) { v[c] = expf(v[c] - mx); s += v[c]; }
        float inv = 1.f / s;
        #pragma unroll
        for (int c = 0; c < 8; ++c) {
            int idx = (c * 3 + p) * 8 + gg;
            float sm = v[c] * inv;
            sPi[idx]  = sm;
            sLPi[idx] = logf(sm);
        }
    }
    if (tid < 8) {                                        // SP softmax over p
        int gg = tid;
        float v0 = lamSP[gg], v1 = lamSP[8 + gg], v2 = lamSP[16 + gg];
        float mx = fmaxf(v0, fmaxf(v1, v2));
        float e0 = expf(v0 - mx), e1 = expf(v1 - mx), e2 = expf(v2 - mx);
        float inv = 1.f / (e0 + e1 + e2);
        sSP[gg] = e0 * inv; sSP[8 + gg] = e1 * inv; sSP[16 + gg] = e2 * inv;
        sLSP[gg] = logf(e0 * inv); sLSP[8 + gg] = logf(e1 * inv); sLSP[16 + gg] = logf(e2 * inv);
    }
    if (tid == 0) {        // Bm gate: one fence per block per launch
        unsigned long sp = 0;
        while (AGENT_LD(&sy[4]) != kMAGIC2) {
            if (++sp > (1UL << 24)) break;
            __builtin_amdgcn_s_sleep(2);
        }
        __threadfence();
    }
    __syncthreads();

    const float* pBm = bmG;
    const int id = blockIdx.x * 2 + sub, t = id / 27, q = id % 27, xb = t * kNPT;
    float* bw = &bW[sub][0];
    unsigned char* xw = &xW[sub][0];

    // ================= phase 1: subtree up-pass =================
    for (int u = lane; u < 121; u += 64) {    // both halves write same values
        int gx;
        if (u == 0)       gx = 13 + q;
        else if (u < 4)   gx = 40  + q * 3  + (u - 1);
        else if (u < 13)  gx = 121 + q * 9  + (u - 4);
        else if (u < 40)  gx = 364 + q * 27 + (u - 13);
        else              gx = 1093 + q * 81 + (u - 40);
        xw[u] = (unsigned char)x[xb + gx];
    }
    __syncthreads();

    for (int e = 3; e >= 0; --e) {
        int cnt = P3[e];
        for (int base = 0; base < cnt; base += 16) {
            int node = base + (n << 1) + h;
            if (node < cnt) {
                float acc[8];
                #pragma unroll
                for (int i = 0; i < 8; ++i) acc[i] = 0.f;
                #pragma unroll
                for (int k = 0; k < 3; ++k) {
                    float bj[8];
                    if (e == 3) {
                        leaf_beta(sPi, pBm, k, xw[40 + 3 * node + k], g, bj);
                    } else {
                        int co = (LO[e + 1] + 3 * node + k) * kRS + g;
                        #pragma unroll
                        for (int j = 0; j < 8; ++j) bj[j] = bw[co + j * 8];
                    }
                    float spg = sSP[k * 8 + g];
                    #pragma unroll
                    for (int i = 0; i < 8; ++i) {
                        float s = 0.f;
                        #pragma unroll
                        for (int j = 0; j < 8; ++j)
                            s = fmaf(sA[((i * 8 + j) * 3 + k) * 8 + g], bj[j], s);
                        acc[i] = fmaf(spg, s, acc[i]);
                    }
                }
                if (e == 0) {
                    #pragma unroll
                    for (int i = 0; i < 8; ++i) bw[i * 8 + g] = acc[i];  // raw tb root
                    int xv = xw[0];
                    float s = 0.f;
                    #pragma unroll
                    for (int i = 0; i < 8; ++i) { acc[i] *= pBm[xv * 64 + i * 8 + g]; s += acc[i]; }
                    float ig = __builtin_amdgcn_rcpf(s);
                    #pragma unroll
                    for (int i = 0; i < 8; ++i)
                        AGENT_ST(&b3[id * 64 + i * 8 + g], acc[i] * ig);
                } else {
                    int slot = LO[e] + node;
                    int xv = xw[slot];
                    float s = 0.f;
                    #pragma unroll
                    for (int i = 0; i < 8; ++i) { acc[i] *= pBm[xv * 64 + i * 8 + g]; s += acc[i]; }
                    float ig = __builtin_amdgcn_rcpf(s);
                    int bo = slot * kRS + g;
                    #pragma unroll
                    for (int i = 0; i < 8; ++i) bw[bo + i * 8] = acc[i] * ig;
                    bw[slot * kRS + 64 + g] = s;
                }
            }
        }
        __syncthreads();
    }
    // signal (h==0 wave wrote b3; its drain covers it)
    __builtin_amdgcn_s_waitcnt(0);
    if (h == 0 && lane == 0)
        __hip_atomic_fetch_add(&trCnt[t * 32], 1u, __ATOMIC_RELAXED,
                               __HIP_MEMORY_SCOPE_AGENT);

    // ================= phase 2: mid (levels 0-3), q==0/h==0 wave per tree ====
    if (q == 0 && h == 0) {
        unsigned long sp = 0;
        while (AGENT_LD(&trCnt[t * 32]) < 27u) {
            if (++sp > (1UL << 22)) break;
            __builtin_amdgcn_s_sleep(1);
        }
        float ellm = 0.f;
        for (int f = 2; f >= 0; --f) {
            int cnt = (f == 2) ? 9 : (f == 1 ? 3 : 1);
            int pl0 = (f == 2) ? 4 : (f == 1 ? 1 : 0);
            int cl0 = (f == 1) ? 4 : 1;
            for (int base = 0; base < cnt; base += 8) {
                int pi = base + n;
                if (pi < cnt) {
                    float acc[8];
                    #pragma unroll
                    for (int i = 0; i < 8; ++i) acc[i] = 0.f;
                    #pragma unroll
                    for (int k = 0; k < 3; ++k) {
                        float bj[8];
                        if (f == 2) {
                            float* src = b3 + (t * 27 + 3 * pi + k) * 64 + g;
                            #pragma unroll
                            for (int j = 0; j < 8; ++j) bj[j] = AGENT_LD(&src[j * 8]);
                        } else {
                            int co = (cl0 + 3 * pi + k) * 64 + g;
                            #pragma unroll
                            for (int j = 0; j < 8; ++j)
                                bj[j] = __half2float(bMidH[co + j * 8]);
                        }
                        float spg = sSP[k * 8 + g];
                        #pragma unroll
                        for (int i = 0; i < 8; ++i) {
                            float s = 0.f;
                            #pragma unroll
                            for (int j = 0; j < 8; ++j)
                                s = fmaf(sA[((i * 8 + j) * 3 + k) * 8 + g], bj[j], s);
                            acc[i] = fmaf(spg, s, acc[i]);
                        }
                    }
                    int slot = pl0 + pi;
                    int xv = x[xb + slot];
                    float s = 0.f;
                    #pragma unroll
                    for (int i = 0; i < 8; ++i) { acc[i] *= pBm[xv * 64 + i * 8 + g]; s += acc[i]; }
                    float ig = __builtin_amdgcn_rcpf(s);
                    int bo = slot * 64 + g;
                    #pragma unroll
                    for (int i = 0; i < 8; ++i)
                        bMidH[bo + i * 8] = __float2half(acc[i] * ig);
                    sMs[slot * 8 + g] = s;
                }
            }
            __builtin_amdgcn_wave_barrier();
        }
        if (n == 0) {     // root: ell Bm term; slot0 := r = Bm/s
            int xv = x[xb];
            float invs = __builtin_amdgcn_rcpf(sMs[g]);
            #pragma unroll
            for (int c = 0; c < 8; ++c)
                ellm += __half2float(bMidH[c * 8 + g]) * pBm[xv * 64 + c * 8 + g];
            #pragma unroll
            for (int c = 0; c < 8; ++c)
                bMidH[c * 8 + g] = __float2half(pBm[xv * 64 + c * 8 + g] * invs);
        }
        __builtin_amdgcn_wave_barrier();
        for (int f = 1; f <= 3; ++f) {
            int cnt = (f == 1) ? 3 : (f == 2 ? 9 : 27);
            int cl0 = (f == 1) ? 1 : (f == 2 ? 4 : 13);
            int pl0 = (f == 1) ? 0 : (f == 2 ? 1 : 4);
            for (int base = 0; base < cnt; base += 8) {
                int ci = base + n;
                if (ci < cnt) {
                    int p = ci % 3;
                    int ps = (pl0 + ci / 3) * 64 + g;
                    float r[8];
                    #pragma unroll
                    for (int i = 0; i < 8; ++i) r[i] = __half2float(bMidH[ps + i * 8]);
                    float bj[8]; float sv = 0.f;
                    if (f == 3) {
                        float* src = b3 + (t * 27 + ci) * 64 + g;
                        #pragma unroll
                        for (int j = 0; j < 8; ++j) bj[j] = AGENT_LD(&src[j * 8]);
                    } else {
                        int co = (cl0 + ci) * 64 + g;
                        #pragma unroll
                        for (int j = 0; j < 8; ++j) bj[j] = __half2float(bMidH[co + j * 8]);
                        sv = sMs[(cl0 + ci) * 8 + g];
                    }
                    float spg = sSP[p * 8 + g];
                    float esum = 0.f, lg = 0.f;
                    float ev[8];
                    #pragma unroll
                    for (int j = 0; j < 8; ++j) {
                        float s1 = 0.f, s2 = 0.f;
                        #pragma unroll
                        for (int i = 0; i < 8; ++i) {
                            int ai = ((i * 8 + j) * 3 + p) * 8 + g;
                            s1 = fmaf(r[i], sA[ai],   s1);
                            s2 = fmaf(r[i], sALA[ai], s2);
                        }
                        float bs = spg * bj[j];
                        ev[j] = bs * s1;
                        lg    = fmaf(bs, s2, lg);
                        esum += ev[j];
                    }
                    lg = fmaf(esum, sLSP[p * 8 + g], lg);
                    int xv = x[xb + cl0 + ci];
                    float Bmv[8];
                    #pragma unroll
                    for (int c = 0; c < 8; ++c) {
                        Bmv[c] = pBm[xv * 64 + c * 8 + g];
                        lg = fmaf(ev[c], Bmv[c], lg);
                    }
                    if (f == 3) {
                        #pragma unroll
                        for (int j = 0; j < 8; ++j)
                            AGENT_ST(&e3[(t * 27 + ci) * 64 + j * 8 + g], ev[j]);
                    } else {
                        int co = (cl0 + ci) * 64 + g;
                        #pragma unroll
                        for (int j = 0; j < 8; ++j)
                            bMidH[co + j * 8] = __float2half(
                                ev[j] * Bmv[j] * __builtin_amdgcn_rcpf(bj[j] * sv));
                    }
                    ellm += lg;
                }
            }
            __builtin_amdgcn_wave_barrier();
        }
        ellm += __shfl_xor(ellm, 8);
        ellm += __shfl_xor(ellm, 16);
        ellm += __shfl_xor(ellm, 32);
        if (n == 0) atomicAdd(&out[t * 8 + g], -ellm);
        __builtin_amdgcn_s_waitcnt(0);
        if (lane == 0) AGENT_ST(&trFlg[t * 32], kMAGIC2);
    }

    // ================= phase 3: subtree down-pass =================
    {
        unsigned long sp = 0;
        while (AGENT_LD(&trFlg[t * 32]) != kMAGIC2) {
            if (++sp > (1UL << 22)) break;
            __builtin_amdgcn_s_sleep(1);
        }
    }
    if (h == 0)
        bw[lane] = AGENT_LD(&e3[id * 64 + lane]) * __builtin_amdgcn_rcpf(bw[lane]);
    __syncthreads();

    float ell = 0.f;
    for (int e = 1; e <= 4; ++e) {
        int cnt = P3[e], pl0 = LO[e - 1];
        for (int base = 0; base < cnt; base += 16) {
            int ci = base + (n << 1) + h;
            if (ci < cnt) {
                int p = ci % 3;
                int ps = (pl0 + ci / 3) * kRS + g;
                float r[8];
                #pragma unroll
                for (int i = 0; i < 8; ++i) r[i] = bw[ps + i * 8];
                float bj[8]; float sv = 0.f;
                int xv;
                if (e == 4) {
                    xv = xw[40 + ci];
                    leaf_beta(sPi, pBm, p, xv, g, bj);
                } else {
                    int slot = LO[e] + ci;
                    xv = xw[slot];
                    int co = slot * kRS + g;
                    #pragma unroll
                    for (int j = 0; j < 8; ++j) bj[j] = bw[co + j * 8];
                    sv = bw[slot * kRS + 64 + g];
                }
                float spg = sSP[p * 8 + g];
                float esum = 0.f, lg = 0.f;
                float ev[8];
                #pragma unroll
                for (int j = 0; j < 8; ++j) {
                    float s1 = 0.f, s2 = 0.f;
                    #pragma unroll
                    for (int i = 0; i < 8; ++i) {
                        int ai = ((i * 8 + j) * 3 + p) * 8 + g;
                        s1 = fmaf(r[i], sA[ai],   s1);
                        s2 = fmaf(r[i], sALA[ai], s2);
                    }
                    float bs = spg * bj[j];
                    ev[j] = bs * s1;
                    lg    = fmaf(bs, s2, lg);
                    esum += ev[j];
                }
                lg = fmaf(esum, sLSP[p * 8 + g], lg);
                float Bmv[8];
                #pragma unroll
                for (int c = 0; c < 8; ++c) {
                    Bmv[c] = pBm[xv * 64 + c * 8 + g];
                    lg = fmaf(ev[c], Bmv[c], lg);
                }
                if (e < 4) {
                    int slot = LO[e] + ci;
                    int co = slot * kRS + g;
                    #pragma unroll
                    for (int j = 0; j < 8; ++j)
                        bw[co + j * 8] = ev[j] * Bmv[j]
                            * __builtin_amdgcn_rcpf(bj[j] * sv);
                } else {
                    #pragma unroll
                    for (int c = 0; c < 8; ++c)
                        lg = fmaf(ev[c], sLPi[(c * 3 + p) * 8 + g], lg);
                }
                ell += lg;
            }
        }
        __syncthreads();
    }

    ell += __shfl_xor(ell, 8);
    ell += __shfl_xor(ell, 16);
    ell += __shfl_xor(ell, 32);
    if (n == 0) atomicAdd(&out[t * 8 + g], -ell);
}

} // namespace

extern "C" void kernel_launch(void* const* d_in, const int* in_sizes, int n_in,
                              void* d_out, int out_size, void* d_ws, size_t ws_size,
                              hipStream_t stream) {
    const float* lamA  = (const float*)d_in[0];
    const float* lamB  = (const float*)d_in[1];
    const float* lamPi = (const float*)d_in[2];
    const float* lamSP = (const float*)d_in[3];
    const int*   x     = (const int*)d_in[4];
    float* out = (float*)d_out;
    unsigned* sy  = (unsigned*)d_ws;        // sync area (32 KB)
    float* bmG = (float*)d_ws + 8192;       // 8192 floats
    float* b3  = bmG + 8192;                // 1728*64
    float* e3  = b3 + 1728 * 64;            // 1728*64

    fused<<<dim3(864), dim3(256), 0, stream>>>(
        lamA, lamB, lamPi, lamSP, x, out, sy, bmG, b3, e3);
}

// Round 11
// 187.076 us; speedup vs baseline: 1.2151x; 1.2151x over previous
//
#include <hip/hip_runtime.h>
#include <hip/hip_fp16.h>

// PosteriorHiddenTreeMarkovModel — MI355X / gfx950
// R11 = R10 with two fixes (structure unchanged):
//  1. __launch_bounds__(256,2): R10's (256,4) halved the wave64 VGPR budget to
//     64 (512/(2*4)) -> massive scratch spills (167 MB HBM traffic, the whole
//     regression). (256,2) budgets 128; R9's identical code compiled at 100.
//     VGPR~100 -> 4 waves/SIMD; LDS 39.4KB -> 4 blocks/CU; 1024 resident >=
//     864 blocks => spin-sync deadlock-free.
//  2. wave h takes node = base + n + 8h (chunk split, banks 8n%32 -> 2-way
//     free) instead of (n<<1)|h (stride doubling -> 4-way, 462K conflicts).
// 2 waves per subtree, 864 blocks = 13.5 waves/CU. Per-tree relaxed-poll sync.

namespace {

constexpr int kNPT = 3280;
constexpr int kRS  = 72;   // subtree record stride: 64 beta + 8 pre-norm sums
constexpr unsigned kMAGIC  = 0x13579BDFu;
constexpr unsigned kMAGIC2 = 0x2468ACEFu;
__device__ __constant__ int LO[6] = {0, 1, 4, 13, 40, 121};
__device__ __constant__ int P3[5] = {1, 3, 9, 27, 81};

#define AGENT_LD(p)    __hip_atomic_load((p), __ATOMIC_RELAXED, __HIP_MEMORY_SCOPE_AGENT)
#define AGENT_ST(p, v) __hip_atomic_store((p), (v), __ATOMIC_RELAXED, __HIP_MEMORY_SCOPE_AGENT)

__device__ __forceinline__ void leaf_beta(const float* __restrict__ sPi,
                                          const float* __restrict__ pBm,
                                          int p, int xv, int g, float* b)
{
    float s = 0.f;
    #pragma unroll
    for (int c = 0; c < 8; ++c) {
        b[c] = sPi[(c * 3 + p) * 8 + g] * pBm[xv * 64 + c * 8 + g];
        s += b[c];
    }
    float ig = __builtin_amdgcn_rcpf(s);
    #pragma unroll
    for (int c = 0; c < 8; ++c) b[c] *= ig;
}

__global__ __launch_bounds__(256, 2)
void fused(const float* __restrict__ lamA, const float* __restrict__ lamB,
           const float* __restrict__ lamPi, const float* __restrict__ lamSP,
           const int* __restrict__ x, float* __restrict__ out,
           unsigned* __restrict__ sy, float* __restrict__ bmG,
           float* __restrict__ b3, float* __restrict__ e3)
{
    const int tid = threadIdx.x, w = tid >> 6, lane = tid & 63;
    const int n = lane >> 3, g = lane & 7;
    const int sub = w >> 1, h = w & 1;
    __shared__ float sA[1536], sALA[1536], sPi[192], sLPi[192], sSP[24], sLSP[24];
    __shared__ float bW[2][40 * kRS];      // per-subtree records (fp32)
    __shared__ __half bMidH[13 * 64];      // mid beta records, fp16
    __shared__ float sMs[13 * 8];          // mid pre-norm sums, fp32
    __shared__ unsigned char xW[2][124];
    unsigned* trCnt = sy + 32;
    unsigned* trFlg = sy + 2080;

    // ---- init gate ----
    if (tid == 0) {
        if (blockIdx.x == 0) {
            for (int i = 0; i < 64; ++i) AGENT_ST(&trCnt[i * 32], 0u);
            __builtin_amdgcn_s_waitcnt(0);
            AGENT_ST(&sy[0], kMAGIC);
        }
        unsigned long sp = 0;
        while (AGENT_LD(&sy[0]) != kMAGIC) {
            if (++sp > (1UL << 24)) break;
            __builtin_amdgcn_s_sleep(2);
        }
    }
    __syncthreads();

    // ================= phase 0: parameters =================
    if (blockIdx.x == 0) {   // Bm softmax -> bmG (transposed [m][c][g]) + flag
        float* rr = &bW[0][0];
        int row = tid >> 2, part = tid & 3;
        int c = row >> 3, gg = row & 7, m0 = part * 32;
        float mx = -1e30f;
        for (int mm = 0; mm < 32; ++mm)
            mx = fmaxf(mx, lamB[(c * 128 + m0 + mm) * 8 + gg]);
        rr[tid] = mx;
        __syncthreads();
        float m4 = fmaxf(fmaxf(rr[row * 4], rr[row * 4 + 1]),
                         fmaxf(rr[row * 4 + 2], rr[row * 4 + 3]));
        float s = 0.f;
        for (int mm = 0; mm < 32; ++mm)
            s += expf(lamB[(c * 128 + m0 + mm) * 8 + gg] - m4);
        rr[256 + tid] = s;
        __syncthreads();
        float stot = rr[256 + row * 4] + rr[256 + row * 4 + 1]
                   + rr[256 + row * 4 + 2] + rr[256 + row * 4 + 3];
        float inv = 1.f / stot;
        for (int mm = 0; mm < 32; ++mm)
            AGENT_ST(&bmG[(m0 + mm) * 64 + c * 8 + gg],
                     expf(lamB[(c * 128 + m0 + mm) * 8 + gg] - m4) * inv);
        __syncthreads();
        if (tid == 0) AGENT_ST(&sy[4], kMAGIC2);
    }
    for (int col = tid; col < 192; col += 256) {          // A softmax over i
        int j = col / 24; int rem = col - j * 24; int p = rem >> 3; int gg = rem & 7;
        float v[8]; float mx = -1e30f;
        #pragma unroll
        for (int i = 0; i < 8; ++i) {
            v[i] = lamA[((i * 8 + j) * 3 + p) * 8 + gg];
            mx = fmaxf(mx, v[i]);
        }
        float s = 0.f;
        #pragma unroll
        for (int i = 0; i < 8; ++i) { v[i] = expf(v[i] - mx); s += v[i]; }
        float inv = 1.f / s;
        #pragma unroll
        for (int i = 0; i < 8; ++i) {
            int idx = ((i * 8 + j) * 3 + p) * 8 + gg;
            float sm = v[i] * inv;
            sA[idx]   = sm;
            sALA[idx] = sm * logf(sm);
        }
    }
    for (int col = tid; col < 24; col += 256) {           // Pi softmax over c
        int p = col >> 3; int gg = col & 7;
        float v[8]; float mx = -1e30f;
        #pragma unroll
        for (int c = 0; c < 8; ++c) {
            v[c] = lamPi[(c * 3 + p) * 8 + gg];
            mx = fmaxf(mx, v[c]);
        }
        float s = 0.f;
        #pragma unroll
        for (int c = 0; c < 8; ++c) { v[c] = expf(v[c] - mx); s += v[c]; }
        float inv = 1.f / s;
        #pragma unroll
        for (int c = 0; c < 8; ++c) {
            int idx = (c * 3 + p) * 8 + gg;
            float sm = v[c] * inv;
            sPi[idx]  = sm;
            sLPi[idx] = logf(sm);
        }
    }
    if (tid < 8) {                                        // SP softmax over p
        int gg = tid;
        float v0 = lamSP[gg], v1 = lamSP[8 + gg], v2 = lamSP[16 + gg];
        float mx = fmaxf(v0, fmaxf(v1, v2));
        float e0 = expf(v0 - mx), e1 = expf(v1 - mx), e2 = expf(v2 - mx);
        float inv = 1.f / (e0 + e1 + e2);
        sSP[gg] = e0 * inv; sSP[8 + gg] = e1 * inv; sSP[16 + gg] = e2 * inv;
        sLSP[gg] = logf(e0 * inv); sLSP[8 + gg] = logf(e1 * inv); sLSP[16 + gg] = logf(e2 * inv);
    }
    if (tid == 0) {        // Bm gate: one fence per block per launch
        unsigned long sp = 0;
        while (AGENT_LD(&sy[4]) != kMAGIC2) {
            if (++sp > (1UL << 24)) break;
            __builtin_amdgcn_s_sleep(2);
        }
        __threadfence();
    }
    __syncthreads();

    const float* pBm = bmG;
    const int id = blockIdx.x * 2 + sub, t = id / 27, q = id % 27, xb = t * kNPT;
    float* bw = &bW[sub][0];
    unsigned char* xw = &xW[sub][0];

    // ================= phase 1: subtree up-pass =================
    for (int u = lane; u < 121; u += 64) {    // both halves write same values
        int gx;
        if (u == 0)       gx = 13 + q;
        else if (u < 4)   gx = 40  + q * 3  + (u - 1);
        else if (u < 13)  gx = 121 + q * 9  + (u - 4);
        else if (u < 40)  gx = 364 + q * 27 + (u - 13);
        else              gx = 1093 + q * 81 + (u - 40);
        xw[u] = (unsigned char)x[xb + gx];
    }
    __syncthreads();

    for (int e = 3; e >= 0; --e) {
        int cnt = P3[e];
        for (int base = 0; base < cnt; base += 16) {
            int node = base + n + (h << 3);     // chunk split: 2-way banks
            if (node < cnt) {
                float acc[8];
                #pragma unroll
                for (int i = 0; i < 8; ++i) acc[i] = 0.f;
                #pragma unroll
                for (int k = 0; k < 3; ++k) {
                    float bj[8];
                    if (e == 3) {
                        leaf_beta(sPi, pBm, k, xw[40 + 3 * node + k], g, bj);
                    } else {
                        int co = (LO[e + 1] + 3 * node + k) * kRS + g;
                        #pragma unroll
                        for (int j = 0; j < 8; ++j) bj[j] = bw[co + j * 8];
                    }
                    float spg = sSP[k * 8 + g];
                    #pragma unroll
                    for (int i = 0; i < 8; ++i) {
                        float s = 0.f;
                        #pragma unroll
                        for (int j = 0; j < 8; ++j)
                            s = fmaf(sA[((i * 8 + j) * 3 + k) * 8 + g], bj[j], s);
                        acc[i] = fmaf(spg, s, acc[i]);
                    }
                }
                if (e == 0) {
                    #pragma unroll
                    for (int i = 0; i < 8; ++i) bw[i * 8 + g] = acc[i];  // raw tb root
                    int xv = xw[0];
                    float s = 0.f;
                    #pragma unroll
                    for (int i = 0; i < 8; ++i) { acc[i] *= pBm[xv * 64 + i * 8 + g]; s += acc[i]; }
                    float ig = __builtin_amdgcn_rcpf(s);
                    #pragma unroll
                    for (int i = 0; i < 8; ++i)
                        AGENT_ST(&b3[id * 64 + i * 8 + g], acc[i] * ig);
                } else {
                    int slot = LO[e] + node;
                    int xv = xw[slot];
                    float s = 0.f;
                    #pragma unroll
                    for (int i = 0; i < 8; ++i) { acc[i] *= pBm[xv * 64 + i * 8 + g]; s += acc[i]; }
                    float ig = __builtin_amdgcn_rcpf(s);
                    int bo = slot * kRS + g;
                    #pragma unroll
                    for (int i = 0; i < 8; ++i) bw[bo + i * 8] = acc[i] * ig;
                    bw[slot * kRS + 64 + g] = s;
                }
            }
        }
        __syncthreads();
    }
    // signal (h==0 wave wrote b3; its drain covers it)
    __builtin_amdgcn_s_waitcnt(0);
    if (h == 0 && lane == 0)
        __hip_atomic_fetch_add(&trCnt[t * 32], 1u, __ATOMIC_RELAXED,
                               __HIP_MEMORY_SCOPE_AGENT);

    // ================= phase 2: mid (levels 0-3), q==0/h==0 wave per tree ====
    if (q == 0 && h == 0) {
        unsigned long sp = 0;
        while (AGENT_LD(&trCnt[t * 32]) < 27u) {
            if (++sp > (1UL << 22)) break;
            __builtin_amdgcn_s_sleep(1);
        }
        float ellm = 0.f;
        for (int f = 2; f >= 0; --f) {
            int cnt = (f == 2) ? 9 : (f == 1 ? 3 : 1);
            int pl0 = (f == 2) ? 4 : (f == 1 ? 1 : 0);
            int cl0 = (f == 1) ? 4 : 1;
            for (int base = 0; base < cnt; base += 8) {
                int pi = base + n;
                if (pi < cnt) {
                    float acc[8];
                    #pragma unroll
                    for (int i = 0; i < 8; ++i) acc[i] = 0.f;
                    #pragma unroll
                    for (int k = 0; k < 3; ++k) {
                        float bj[8];
                        if (f == 2) {
                            float* src = b3 + (t * 27 + 3 * pi + k) * 64 + g;
                            #pragma unroll
                            for (int j = 0; j < 8; ++j) bj[j] = AGENT_LD(&src[j * 8]);
                        } else {
                            int co = (cl0 + 3 * pi + k) * 64 + g;
                            #pragma unroll
                            for (int j = 0; j < 8; ++j)
                                bj[j] = __half2float(bMidH[co + j * 8]);
                        }
                        float spg = sSP[k * 8 + g];
                        #pragma unroll
                        for (int i = 0; i < 8; ++i) {
                            float s = 0.f;
                            #pragma unroll
                            for (int j = 0; j < 8; ++j)
                                s = fmaf(sA[((i * 8 + j) * 3 + k) * 8 + g], bj[j], s);
                            acc[i] = fmaf(spg, s, acc[i]);
                        }
                    }
                    int slot = pl0 + pi;
                    int xv = x[xb + slot];
                    float s = 0.f;
                    #pragma unroll
                    for (int i = 0; i < 8; ++i) { acc[i] *= pBm[xv * 64 + i * 8 + g]; s += acc[i]; }
                    float ig = __builtin_amdgcn_rcpf(s);
                    int bo = slot * 64 + g;
                    #pragma unroll
                    for (int i = 0; i < 8; ++i)
                        bMidH[bo + i * 8] = __float2half(acc[i] * ig);
                    sMs[slot * 8 + g] = s;
                }
            }
            __builtin_amdgcn_wave_barrier();
        }
        if (n == 0) {     // root: ell Bm term; slot0 := r = Bm/s
            int xv = x[xb];
            float invs = __builtin_amdgcn_rcpf(sMs[g]);
            #pragma unroll
            for (int c = 0; c < 8; ++c)
                ellm += __half2float(bMidH[c * 8 + g]) * pBm[xv * 64 + c * 8 + g];
            #pragma unroll
            for (int c = 0; c < 8; ++c)
                bMidH[c * 8 + g] = __float2half(pBm[xv * 64 + c * 8 + g] * invs);
        }
        __builtin_amdgcn_wave_barrier();
        for (int f = 1; f <= 3; ++f) {
            int cnt = (f == 1) ? 3 : (f == 2 ? 9 : 27);
            int cl0 = (f == 1) ? 1 : (f == 2 ? 4 : 13);
            int pl0 = (f == 1) ? 0 : (f == 2 ? 1 : 4);
            for (int base = 0; base < cnt; base += 8) {
                int ci = base + n;
                if (ci < cnt) {
                    int p = ci % 3;
                    int ps = (pl0 + ci / 3) * 64 + g;
                    float r[8];
                    #pragma unroll
                    for (int i = 0; i < 8; ++i) r[i] = __half2float(bMidH[ps + i * 8]);
                    float bj[8]; float sv = 0.f;
                    if (f == 3) {
                        float* src = b3 + (t * 27 + ci) * 64 + g;
                        #pragma unroll
                        for (int j = 0; j < 8; ++j) bj[j] = AGENT_LD(&src[j * 8]);
                    } else {
                        int co = (cl0 + ci) * 64 + g;
                        #pragma unroll
                        for (int j = 0; j < 8; ++j) bj[j] = __half2float(bMidH[co + j * 8]);
                        sv = sMs[(cl0 + ci) * 8 + g];
                    }
                    float spg = sSP[p * 8 + g];
                    float esum = 0.f, lg = 0.f;
                    float ev[8];
                    #pragma unroll
                    for (int j = 0; j < 8; ++j) {
                        float s1 = 0.f, s2 = 0.f;
                        #pragma unroll
                        for (int i = 0; i < 8; ++i) {
                            int ai = ((i * 8 + j) * 3 + p) * 8 + g;
                            s1 = fmaf(r[i], sA[ai],   s1);
                            s2 = fmaf(r[i], sALA[ai], s2);
                        }
                        float bs = spg * bj[j];
                        ev[j] = bs * s1;
                        lg    = fmaf(bs, s2, lg);
                        esum += ev[j];
                    }
                    lg = fmaf(esum, sLSP[p * 8 + g], lg);
                    int xv = x[xb + cl0 + ci];
                    float Bmv[8];
                    #pragma unroll
                    for (int c = 0; c < 8; ++c) {
                        Bmv[c] = pBm[xv * 64 + c * 8 + g];
                        lg = fmaf(ev[c], Bmv[c], lg);
                    }
                    if (f == 3) {
                        #pragma unroll
                        for (int j = 0; j < 8; ++j)
                            AGENT_ST(&e3[(t * 27 + ci) * 64 + j * 8 + g], ev[j]);
                    } else {
                        int co = (cl0 + ci) * 64 + g;
                        #pragma unroll
                        for (int j = 0; j < 8; ++j)
                            bMidH[co + j * 8] = __float2half(
                                ev[j] * Bmv[j] * __builtin_amdgcn_rcpf(bj[j] * sv));
                    }
                    ellm += lg;
                }
            }
            __builtin_amdgcn_wave_barrier();
        }
        ellm += __shfl_xor(ellm, 8);
        ellm += __shfl_xor(ellm, 16);
        ellm += __shfl_xor(ellm, 32);
        if (n == 0) atomicAdd(&out[t * 8 + g], -ellm);
        __builtin_amdgcn_s_waitcnt(0);
        if (lane == 0) AGENT_ST(&trFlg[t * 32], kMAGIC2);
    }

    // ================= phase 3: subtree down-pass =================
    {
        unsigned long sp = 0;
        while (AGENT_LD(&trFlg[t * 32]) != kMAGIC2) {
            if (++sp > (1UL << 22)) break;
            __builtin_amdgcn_s_sleep(1);
        }
    }
    if (h == 0)
        bw[lane] = AGENT_LD(&e3[id * 64 + lane]) * __builtin_amdgcn_rcpf(bw[lane]);
    __syncthreads();

    float ell = 0.f;
    for (int e = 1; e <= 4; ++e) {
        int cnt = P3[e], pl0 = LO[e - 1];
        for (int base = 0; base < cnt; base += 16) {
            int ci = base + n + (h << 3);       // chunk split: 2-way banks
            if (ci < cnt) {
                int p = ci % 3;
                int ps = (pl0 + ci / 3) * kRS + g;
                float r[8];
                #pragma unroll
                for (int i = 0; i < 8; ++i) r[i] = bw[ps + i * 8];
                float bj[8]; float sv = 0.f;
                int xv;
                if (e == 4) {
                    xv = xw[40 + ci];
                    leaf_beta(sPi, pBm, p, xv, g, bj);
                } else {
                    int slot = LO[e] + ci;
                    xv = xw[slot];
                    int co = slot * kRS + g;
                    #pragma unroll
                    for (int j = 0; j < 8; ++j) bj[j] = bw[co + j * 8];
                    sv = bw[slot * kRS + 64 + g];
                }
                float spg = sSP[p * 8 + g];
                float esum = 0.f, lg = 0.f;
                float ev[8];
                #pragma unroll
                for (int j = 0; j < 8; ++j) {
                    float s1 = 0.f, s2 = 0.f;
                    #pragma unroll
                    for (int i = 0; i < 8; ++i) {
                        int ai = ((i * 8 + j) * 3 + p) * 8 + g;
                        s1 = fmaf(r[i], sA[ai],   s1);
                        s2 = fmaf(r[i], sALA[ai], s2);
                    }
                    float bs = spg * bj[j];
                    ev[j] = bs * s1;
                    lg    = fmaf(bs, s2, lg);
                    esum += ev[j];
                }
                lg = fmaf(esum, sLSP[p * 8 + g], lg);
                float Bmv[8];
                #pragma unroll
                for (int c = 0; c < 8; ++c) {
                    Bmv[c] = pBm[xv * 64 + c * 8 + g];
                    lg = fmaf(ev[c], Bmv[c], lg);
                }
                if (e < 4) {
                    int slot = LO[e] + ci;
                    int co = slot * kRS + g;
                    #pragma unroll
                    for (int j = 0; j < 8; ++j)
                        bw[co + j * 8] = ev[j] * Bmv[j]
                            * __builtin_amdgcn_rcpf(bj[j] * sv);
                } else {
                    #pragma unroll
                    for (int c = 0; c < 8; ++c)
                        lg = fmaf(ev[c], sLPi[(c * 3 + p) * 8 + g], lg);
                }
                ell += lg;
            }
        }
        __syncthreads();
    }

    ell += __shfl_xor(ell, 8);
    ell += __shfl_xor(ell, 16);
    ell += __shfl_xor(ell, 32);
    if (n == 0) atomicAdd(&out[t * 8 + g], -ell);
}

} // namespace

extern "C" void kernel_launch(void* const* d_in, const int* in_sizes, int n_in,
                              void* d_out, int out_size, void* d_ws, size_t ws_size,
                              hipStream_t stream) {
    const float* lamA  = (const float*)d_in[0];
    const float* lamB  = (const float*)d_in[1];
    const float* lamPi = (const float*)d_in[2];
    const float* lamSP = (const float*)d_in[3];
    const int*   x     = (const int*)d_in[4];
    float* out = (float*)d_out;
    unsigned* sy  = (unsigned*)d_ws;        // sync area (32 KB)
    float* bmG = (float*)d_ws + 8192;       // 8192 floats
    float* b3  = bmG + 8192;                // 1728*64
    float* e3  = b3 + 1728 * 64;            // 1728*64

    fused<<<dim3(864), dim3(256), 0, stream>>>(
        lamA, lamB, lamPi, lamSP, x, out, sy, bmG, b3, e3);
}

// Round 12
// 171.293 us; speedup vs baseline: 1.3270x; 1.0921x over previous
//
#include <hip/hip_runtime.h>
#include <hip/hip_fp16.h>

// PosteriorHiddenTreeMarkovModel — MI355X / gfx950
// R12 = R11 + vectorized A reads. R11 post-mortem: doubling waves left
// VALUBusy at ~18% and wall time flat -> per-CU LDS instruction issue is the
// saturated pipe (ds_read_b32:fmaf ~ 1:1 in hot loops at ~5.8 vs 2 cyc).
// Fix: A and A*logA stored g-major, sAg[(g*3+p)*68 + j*8 + i] (row 272B,
// 16B aligned) -> per (node,j) the 8 i-values load as 2x ds_read_b128.
// Up-pass (p=k uniform): bases 12g+4k+8j mod 32 = 8 distinct 4-bank groups ->
// conflict-free. Down-pass (p per node): 3-way on b128 — still ~3x fewer
// LDS instructions per node (233->89 up, 152->56 down).
// LDS 40.2KB <= 40.96KB keeps 4 blocks/CU (864 blocks all resident).
// Structure unchanged from R11: 2 waves/subtree, 864 blocks, per-tree
// relaxed-poll sync, fp16 bMid, chunk split node = base + n + 8h.

namespace {

constexpr int kNPT = 3280;
constexpr int kRS  = 72;   // subtree record stride: 64 beta + 8 pre-norm sums
constexpr int kAS  = 68;   // A row stride (floats) per (g,p): 64 + 4 pad
constexpr unsigned kMAGIC  = 0x13579BDFu;
constexpr unsigned kMAGIC2 = 0x2468ACEFu;
__device__ __constant__ int LO[6] = {0, 1, 4, 13, 40, 121};
__device__ __constant__ int P3[5] = {1, 3, 9, 27, 81};

#define AGENT_LD(p)    __hip_atomic_load((p), __ATOMIC_RELAXED, __HIP_MEMORY_SCOPE_AGENT)
#define AGENT_ST(p, v) __hip_atomic_store((p), (v), __ATOMIC_RELAXED, __HIP_MEMORY_SCOPE_AGENT)

__device__ __forceinline__ void leaf_beta(const float* __restrict__ sPi,
                                          const float* __restrict__ pBm,
                                          int p, int xv, int g, float* b)
{
    float s = 0.f;
    #pragma unroll
    for (int c = 0; c < 8; ++c) {
        b[c] = sPi[(c * 3 + p) * 8 + g] * pBm[xv * 64 + c * 8 + g];
        s += b[c];
    }
    float ig = __builtin_amdgcn_rcpf(s);
    #pragma unroll
    for (int c = 0; c < 8; ++c) b[c] *= ig;
}

// acc[i] += (spg*bj[j]) * A[i][j]  over j, A row = sAg + (g*3+p)*kAS
__device__ __forceinline__ void matvec_acc(const float* __restrict__ arow,
                                           const float* __restrict__ bj,
                                           float spg, float* acc)
{
    #pragma unroll
    for (int j = 0; j < 8; ++j) {
        float4 a0 = *(const float4*)(arow + j * 8);
        float4 a1 = *(const float4*)(arow + j * 8 + 4);
        float cjv = spg * bj[j];
        acc[0] = fmaf(a0.x, cjv, acc[0]); acc[1] = fmaf(a0.y, cjv, acc[1]);
        acc[2] = fmaf(a0.z, cjv, acc[2]); acc[3] = fmaf(a0.w, cjv, acc[3]);
        acc[4] = fmaf(a1.x, cjv, acc[4]); acc[5] = fmaf(a1.y, cjv, acc[5]);
        acc[6] = fmaf(a1.z, cjv, acc[6]); acc[7] = fmaf(a1.w, cjv, acc[7]);
    }
}

__global__ __launch_bounds__(256, 2)
void fused(const float* __restrict__ lamA, const float* __restrict__ lamB,
           const float* __restrict__ lamPi, const float* __restrict__ lamSP,
           const int* __restrict__ x, float* __restrict__ out,
           unsigned* __restrict__ sy, float* __restrict__ bmG,
           float* __restrict__ b3, float* __restrict__ e3)
{
    const int tid = threadIdx.x, w = tid >> 6, lane = tid & 63;
    const int n = lane >> 3, g = lane & 7;
    const int sub = w >> 1, h = w & 1;
    __shared__ __align__(16) float sAg[24 * kAS];   // A   [g][p][j][i]
    __shared__ __align__(16) float sLAg[24 * kAS];  // AlogA same layout
    __shared__ float sPi[192], sLPi[192], sSP[24], sLSP[24];
    __shared__ float bW[2][40 * kRS];
    __shared__ __half bMidH[13 * 64];
    __shared__ float sMs[13 * 8];
    __shared__ unsigned char xW[2][124];
    unsigned* trCnt = sy + 32;
    unsigned* trFlg = sy + 2080;

    // ---- init gate ----
    if (tid == 0) {
        if (blockIdx.x == 0) {
            for (int i = 0; i < 64; ++i) AGENT_ST(&trCnt[i * 32], 0u);
            __builtin_amdgcn_s_waitcnt(0);
            AGENT_ST(&sy[0], kMAGIC);
        }
        unsigned long sp = 0;
        while (AGENT_LD(&sy[0]) != kMAGIC) {
            if (++sp > (1UL << 24)) break;
            __builtin_amdgcn_s_sleep(2);
        }
    }
    __syncthreads();

    // ================= phase 0: parameters =================
    if (blockIdx.x == 0) {   // Bm softmax -> bmG (transposed [m][c][g]) + flag
        float* rr = &bW[0][0];
        int row = tid >> 2, part = tid & 3;
        int c = row >> 3, gg = row & 7, m0 = part * 32;
        float mx = -1e30f;
        for (int mm = 0; mm < 32; ++mm)
            mx = fmaxf(mx, lamB[(c * 128 + m0 + mm) * 8 + gg]);
        rr[tid] = mx;
        __syncthreads();
        float m4 = fmaxf(fmaxf(rr[row * 4], rr[row * 4 + 1]),
                         fmaxf(rr[row * 4 + 2], rr[row * 4 + 3]));
        float s = 0.f;
        for (int mm = 0; mm < 32; ++mm)
            s += expf(lamB[(c * 128 + m0 + mm) * 8 + gg] - m4);
        rr[256 + tid] = s;
        __syncthreads();
        float stot = rr[256 + row * 4] + rr[256 + row * 4 + 1]
                   + rr[256 + row * 4 + 2] + rr[256 + row * 4 + 3];
        float inv = 1.f / stot;
        for (int mm = 0; mm < 32; ++mm)
            AGENT_ST(&bmG[(m0 + mm) * 64 + c * 8 + gg],
                     expf(lamB[(c * 128 + m0 + mm) * 8 + gg] - m4) * inv);
        __syncthreads();
        if (tid == 0) AGENT_ST(&sy[4], kMAGIC2);
    }
    for (int col = tid; col < 192; col += 256) {   // A softmax over i -> g-major
        int j = col / 24; int rem = col - j * 24; int p = rem >> 3; int gg = rem & 7;
        float v[8]; float mx = -1e30f;
        #pragma unroll
        for (int i = 0; i < 8; ++i) {
            v[i] = lamA[((i * 8 + j) * 3 + p) * 8 + gg];
            mx = fmaxf(mx, v[i]);
        }
        float s = 0.f;
        #pragma unroll
        for (int i = 0; i < 8; ++i) { v[i] = expf(v[i] - mx); s += v[i]; }
        float inv = 1.f / s;
        int base = (gg * 3 + p) * kAS + j * 8;
        #pragma unroll
        for (int i = 0; i < 8; ++i) {
            float sm = v[i] * inv;
            sAg[base + i]  = sm;
            sLAg[base + i] = sm * logf(sm);
        }
    }
    for (int col = tid; col < 24; col += 256) {    // Pi softmax over c
        int p = col >> 3; int gg = col & 7;
        float v[8]; float mx = -1e30f;
        #pragma unroll
        for (int c = 0; c < 8; ++c) {
            v[c] = lamPi[(c * 3 + p) * 8 + gg];
            mx = fmaxf(mx, v[c]);
        }
        float s = 0.f;
        #pragma unroll
        for (int c = 0; c < 8; ++c) { v[c] = expf(v[c] - mx); s += v[c]; }
        float inv = 1.f / s;
        #pragma unroll
        for (int c = 0; c < 8; ++c) {
            int idx = (c * 3 + p) * 8 + gg;
            float sm = v[c] * inv;
            sPi[idx]  = sm;
            sLPi[idx] = logf(sm);
        }
    }
    if (tid < 8) {                                 // SP softmax over p
        int gg = tid;
        float v0 = lamSP[gg], v1 = lamSP[8 + gg], v2 = lamSP[16 + gg];
        float mx = fmaxf(v0, fmaxf(v1, v2));
        float e0 = expf(v0 - mx), e1 = expf(v1 - mx), e2 = expf(v2 - mx);
        float inv = 1.f / (e0 + e1 + e2);
        sSP[gg] = e0 * inv; sSP[8 + gg] = e1 * inv; sSP[16 + gg] = e2 * inv;
        sLSP[gg] = logf(e0 * inv); sLSP[8 + gg] = logf(e1 * inv); sLSP[16 + gg] = logf(e2 * inv);
    }
    if (tid == 0) {        // Bm gate: one fence per block per launch
        unsigned long sp = 0;
        while (AGENT_LD(&sy[4]) != kMAGIC2) {
            if (++sp > (1UL << 24)) break;
            __builtin_amdgcn_s_sleep(2);
        }
        __threadfence();
    }
    __syncthreads();

    const float* pBm = bmG;
    const int id = blockIdx.x * 2 + sub, t = id / 27, q = id % 27, xb = t * kNPT;
    float* bw = &bW[sub][0];
    unsigned char* xw = &xW[sub][0];

    // ================= phase 1: subtree up-pass =================
    for (int u = lane; u < 121; u += 64) {
        int gx;
        if (u == 0)       gx = 13 + q;
        else if (u < 4)   gx = 40  + q * 3  + (u - 1);
        else if (u < 13)  gx = 121 + q * 9  + (u - 4);
        else if (u < 40)  gx = 364 + q * 27 + (u - 13);
        else              gx = 1093 + q * 81 + (u - 40);
        xw[u] = (unsigned char)x[xb + gx];
    }
    __syncthreads();

    for (int e = 3; e >= 0; --e) {
        int cnt = P3[e];
        for (int base = 0; base < cnt; base += 16) {
            int node = base + n + (h << 3);
            if (node < cnt) {
                float acc[8];
                #pragma unroll
                for (int i = 0; i < 8; ++i) acc[i] = 0.f;
                #pragma unroll
                for (int k = 0; k < 3; ++k) {
                    float bj[8];
                    if (e == 3) {
                        leaf_beta(sPi, pBm, k, xw[40 + 3 * node + k], g, bj);
                    } else {
                        int co = (LO[e + 1] + 3 * node + k) * kRS + g;
                        #pragma unroll
                        for (int j = 0; j < 8; ++j) bj[j] = bw[co + j * 8];
                    }
                    matvec_acc(&sAg[(g * 3 + k) * kAS], bj, sSP[k * 8 + g], acc);
                }
                if (e == 0) {
                    #pragma unroll
                    for (int i = 0; i < 8; ++i) bw[i * 8 + g] = acc[i];  // raw tb root
                    int xv = xw[0];
                    float s = 0.f;
                    #pragma unroll
                    for (int i = 0; i < 8; ++i) { acc[i] *= pBm[xv * 64 + i * 8 + g]; s += acc[i]; }
                    float ig = __builtin_amdgcn_rcpf(s);
                    #pragma unroll
                    for (int i = 0; i < 8; ++i)
                        AGENT_ST(&b3[id * 64 + i * 8 + g], acc[i] * ig);
                } else {
                    int slot = LO[e] + node;
                    int xv = xw[slot];
                    float s = 0.f;
                    #pragma unroll
                    for (int i = 0; i < 8; ++i) { acc[i] *= pBm[xv * 64 + i * 8 + g]; s += acc[i]; }
                    float ig = __builtin_amdgcn_rcpf(s);
                    int bo = slot * kRS + g;
                    #pragma unroll
                    for (int i = 0; i < 8; ++i) bw[bo + i * 8] = acc[i] * ig;
                    bw[slot * kRS + 64 + g] = s;
                }
            }
        }
        __syncthreads();
    }
    __builtin_amdgcn_s_waitcnt(0);
    if (h == 0 && lane == 0)
        __hip_atomic_fetch_add(&trCnt[t * 32], 1u, __ATOMIC_RELAXED,
                               __HIP_MEMORY_SCOPE_AGENT);

    // ================= phase 2: mid (levels 0-3), q==0/h==0 wave per tree ====
    if (q == 0 && h == 0) {
        unsigned long sp = 0;
        while (AGENT_LD(&trCnt[t * 32]) < 27u) {
            if (++sp > (1UL << 22)) break;
            __builtin_amdgcn_s_sleep(1);
        }
        float ellm = 0.f;
        for (int f = 2; f >= 0; --f) {
            int cnt = (f == 2) ? 9 : (f == 1 ? 3 : 1);
            int pl0 = (f == 2) ? 4 : (f == 1 ? 1 : 0);
            int cl0 = (f == 1) ? 4 : 1;
            for (int base = 0; base < cnt; base += 8) {
                int pi = base + n;
                if (pi < cnt) {
                    float acc[8];
                    #pragma unroll
                    for (int i = 0; i < 8; ++i) acc[i] = 0.f;
                    #pragma unroll
                    for (int k = 0; k < 3; ++k) {
                        float bj[8];
                        if (f == 2) {
                            float* src = b3 + (t * 27 + 3 * pi + k) * 64 + g;
                            #pragma unroll
                            for (int j = 0; j < 8; ++j) bj[j] = AGENT_LD(&src[j * 8]);
                        } else {
                            int co = (cl0 + 3 * pi + k) * 64 + g;
                            #pragma unroll
                            for (int j = 0; j < 8; ++j)
                                bj[j] = __half2float(bMidH[co + j * 8]);
                        }
                        matvec_acc(&sAg[(g * 3 + k) * kAS], bj, sSP[k * 8 + g], acc);
                    }
                    int slot = pl0 + pi;
                    int xv = x[xb + slot];
                    float s = 0.f;
                    #pragma unroll
                    for (int i = 0; i < 8; ++i) { acc[i] *= pBm[xv * 64 + i * 8 + g]; s += acc[i]; }
                    float ig = __builtin_amdgcn_rcpf(s);
                    int bo = slot * 64 + g;
                    #pragma unroll
                    for (int i = 0; i < 8; ++i)
                        bMidH[bo + i * 8] = __float2half(acc[i] * ig);
                    sMs[slot * 8 + g] = s;
                }
            }
            __builtin_amdgcn_wave_barrier();
        }
        if (n == 0) {     // root: ell Bm term; slot0 := r = Bm/s
            int xv = x[xb];
            float invs = __builtin_amdgcn_rcpf(sMs[g]);
            #pragma unroll
            for (int c = 0; c < 8; ++c)
                ellm += __half2float(bMidH[c * 8 + g]) * pBm[xv * 64 + c * 8 + g];
            #pragma unroll
            for (int c = 0; c < 8; ++c)
                bMidH[c * 8 + g] = __float2half(pBm[xv * 64 + c * 8 + g] * invs);
        }
        __builtin_amdgcn_wave_barrier();
        for (int f = 1; f <= 3; ++f) {
            int cnt = (f == 1) ? 3 : (f == 2 ? 9 : 27);
            int cl0 = (f == 1) ? 1 : (f == 2 ? 4 : 13);
            int pl0 = (f == 1) ? 0 : (f == 2 ? 1 : 4);
            for (int base = 0; base < cnt; base += 8) {
                int ci = base + n;
                if (ci < cnt) {
                    int p = ci % 3;
                    int ps = (pl0 + ci / 3) * 64 + g;
                    float r[8];
                    #pragma unroll
                    for (int i = 0; i < 8; ++i) r[i] = __half2float(bMidH[ps + i * 8]);
                    float bj[8]; float sv = 0.f;
                    if (f == 3) {
                        float* src = b3 + (t * 27 + ci) * 64 + g;
                        #pragma unroll
                        for (int j = 0; j < 8; ++j) bj[j] = AGENT_LD(&src[j * 8]);
                    } else {
                        int co = (cl0 + ci) * 64 + g;
                        #pragma unroll
                        for (int j = 0; j < 8; ++j) bj[j] = __half2float(bMidH[co + j * 8]);
                        sv = sMs[(cl0 + ci) * 8 + g];
                    }
                    float spg = sSP[p * 8 + g];
                    const float* arow = &sAg[(g * 3 + p) * kAS];
                    const float* lrow = &sLAg[(g * 3 + p) * kAS];
                    float esum = 0.f, lg = 0.f;
                    float ev[8];
                    #pragma unroll
                    for (int j = 0; j < 8; ++j) {
                        float4 a0 = *(const float4*)(arow + j * 8);
                        float4 a1 = *(const float4*)(arow + j * 8 + 4);
                        float4 l0 = *(const float4*)(lrow + j * 8);
                        float4 l1 = *(const float4*)(lrow + j * 8 + 4);
                        float s1 = r[0] * a0.x; s1 = fmaf(r[1], a0.y, s1);
                        s1 = fmaf(r[2], a0.z, s1); s1 = fmaf(r[3], a0.w, s1);
                        s1 = fmaf(r[4], a1.x, s1); s1 = fmaf(r[5], a1.y, s1);
                        s1 = fmaf(r[6], a1.z, s1); s1 = fmaf(r[7], a1.w, s1);
                        float s2 = r[0] * l0.x; s2 = fmaf(r[1], l0.y, s2);
                        s2 = fmaf(r[2], l0.z, s2); s2 = fmaf(r[3], l0.w, s2);
                        s2 = fmaf(r[4], l1.x, s2); s2 = fmaf(r[5], l1.y, s2);
                        s2 = fmaf(r[6], l1.z, s2); s2 = fmaf(r[7], l1.w, s2);
                        float bs = spg * bj[j];
                        ev[j] = bs * s1;
                        lg    = fmaf(bs, s2, lg);
                        esum += ev[j];
                    }
                    lg = fmaf(esum, sLSP[p * 8 + g], lg);
                    int xv = x[xb + cl0 + ci];
                    float Bmv[8];
                    #pragma unroll
                    for (int c = 0; c < 8; ++c) {
                        Bmv[c] = pBm[xv * 64 + c * 8 + g];
                        lg = fmaf(ev[c], Bmv[c], lg);
                    }
                    if (f == 3) {
                        #pragma unroll
                        for (int j = 0; j < 8; ++j)
                            AGENT_ST(&e3[(t * 27 + ci) * 64 + j * 8 + g], ev[j]);
                    } else {
                        int co = (cl0 + ci) * 64 + g;
                        #pragma unroll
                        for (int j = 0; j < 8; ++j)
                            bMidH[co + j * 8] = __float2half(
                                ev[j] * Bmv[j] * __builtin_amdgcn_rcpf(bj[j] * sv));
                    }
                    ellm += lg;
                }
            }
            __builtin_amdgcn_wave_barrier();
        }
        ellm += __shfl_xor(ellm, 8);
        ellm += __shfl_xor(ellm, 16);
        ellm += __shfl_xor(ellm, 32);
        if (n == 0) atomicAdd(&out[t * 8 + g], -ellm);
        __builtin_amdgcn_s_waitcnt(0);
        if (lane == 0) AGENT_ST(&trFlg[t * 32], kMAGIC2);
    }

    // ================= phase 3: subtree down-pass =================
    {
        unsigned long sp = 0;
        while (AGENT_LD(&trFlg[t * 32]) != kMAGIC2) {
            if (++sp > (1UL << 22)) break;
            __builtin_amdgcn_s_sleep(1);
        }
    }
    if (h == 0)
        bw[lane] = AGENT_LD(&e3[id * 64 + lane]) * __builtin_amdgcn_rcpf(bw[lane]);
    __syncthreads();

    float ell = 0.f;
    for (int e = 1; e <= 4; ++e) {
        int cnt = P3[e], pl0 = LO[e - 1];
        for (int base = 0; base < cnt; base += 16) {
            int ci = base + n + (h << 3);
            if (ci < cnt) {
                int p = ci % 3;
                int ps = (pl0 + ci / 3) * kRS + g;
                float r[8];
                #pragma unroll
                for (int i = 0; i < 8; ++i) r[i] = bw[ps + i * 8];
                float bj[8]; float sv = 0.f;
                int xv;
                if (e == 4) {
                    xv = xw[40 + ci];
                    leaf_beta(sPi, pBm, p, xv, g, bj);
                } else {
                    int slot = LO[e] + ci;
                    xv = xw[slot];
                    int co = slot * kRS + g;
                    #pragma unroll
                    for (int j = 0; j < 8; ++j) bj[j] = bw[co + j * 8];
                    sv = bw[slot * kRS + 64 + g];
                }
                float spg = sSP[p * 8 + g];
                const float* arow = &sAg[(g * 3 + p) * kAS];
                const float* lrow = &sLAg[(g * 3 + p) * kAS];
                float esum = 0.f, lg = 0.f;
                float ev[8];
                #pragma unroll
                for (int j = 0; j < 8; ++j) {
                    float4 a0 = *(const float4*)(arow + j * 8);
                    float4 a1 = *(const float4*)(arow + j * 8 + 4);
                    float4 l0 = *(const float4*)(lrow + j * 8);
                    float4 l1 = *(const float4*)(lrow + j * 8 + 4);
                    float s1 = r[0] * a0.x; s1 = fmaf(r[1], a0.y, s1);
                    s1 = fmaf(r[2], a0.z, s1); s1 = fmaf(r[3], a0.w, s1);
                    s1 = fmaf(r[4], a1.x, s1); s1 = fmaf(r[5], a1.y, s1);
                    s1 = fmaf(r[6], a1.z, s1); s1 = fmaf(r[7], a1.w, s1);
                    float s2 = r[0] * l0.x; s2 = fmaf(r[1], l0.y, s2);
                    s2 = fmaf(r[2], l0.z, s2); s2 = fmaf(r[3], l0.w, s2);
                    s2 = fmaf(r[4], l1.x, s2); s2 = fmaf(r[5], l1.y, s2);
                    s2 = fmaf(r[6], l1.z, s2); s2 = fmaf(r[7], l1.w, s2);
                    float bs = spg * bj[j];
                    ev[j] = bs * s1;
                    lg    = fmaf(bs, s2, lg);
                    esum += ev[j];
                }
                lg = fmaf(esum, sLSP[p * 8 + g], lg);
                float Bmv[8];
                #pragma unroll
                for (int c = 0; c < 8; ++c) {
                    Bmv[c] = pBm[xv * 64 + c * 8 + g];
                    lg = fmaf(ev[c], Bmv[c], lg);
                }
                if (e < 4) {
                    int slot = LO[e] + ci;
                    int co = slot * kRS + g;
                    #pragma unroll
                    for (int j = 0; j < 8; ++j)
                        bw[co + j * 8] = ev[j] * Bmv[j]
                            * __builtin_amdgcn_rcpf(bj[j] * sv);
                } else {
                    #pragma unroll
                    for (int c = 0; c < 8; ++c)
                        lg = fmaf(ev[c], sLPi[(c * 3 + p) * 8 + g], lg);
                }
                ell += lg;
            }
        }
        __syncthreads();
    }

    ell += __shfl_xor(ell, 8);
    ell += __shfl_xor(ell, 16);
    ell += __shfl_xor(ell, 32);
    if (n == 0) atomicAdd(&out[t * 8 + g], -ell);
}

} // namespace

extern "C" void kernel_launch(void* const* d_in, const int* in_sizes, int n_in,
                              void* d_out, int out_size, void* d_ws, size_t ws_size,
                              hipStream_t stream) {
    const float* lamA  = (const float*)d_in[0];
    const float* lamB  = (const float*)d_in[1];
    const float* lamPi = (const float*)d_in[2];
    const float* lamSP = (const float*)d_in[3];
    const int*   x     = (const int*)d_in[4];
    float* out = (float*)d_out;
    unsigned* sy  = (unsigned*)d_ws;        // sync area (32 KB)
    float* bmG = (float*)d_ws + 8192;       // 8192 floats
    float* b3  = bmG + 8192;                // 1728*64
    float* e3  = b3 + 1728 * 64;            // 1728*64

    fused<<<dim3(864), dim3(256), 0, stream>>>(
        lamA, lamB, lamPi, lamSP, x, out, sy, bmG, b3, e3);
}

// Round 13
// 141.944 us; speedup vs baseline: 1.6014x; 1.2068x over previous
//
#include <hip/hip_runtime.h>
#include <hip/hip_fp16.h>

// PosteriorHiddenTreeMarkovModel — MI355X / gfx950
// R13 = R9 structure + R12 vectorized A + cached mid reads.
// Post-mortems: R10-12's 864-block/h-split config is strictly worse than R9's
// 432-block wave-per-subtree (anti-TLP: 92 vs 110-127 us) and the h-split
// caused 4-way bw-record conflicts (3.5M cycles). Revert to: 432 blocks,
// 4 subtrees/block, 1 wave per subtree, wave-barriers only in hot loops.
// Keep from R12: A and A*logA in g-major rows sAg[(g*3+p)*68+j*8+i] read as
// ds_read_b128 pairs (conflict-free when p is wave-uniform).
// New: mid wave does ONE __threadfence after the trCnt poll, then reads b3
// with normal cached loads (L2-hot ~200cy) instead of per-element
// coherence-point AGENT_LD (~500cy). Stale lines are benign: inputs restored
// before every launch => any stale b3 line is bit-identical.
// LDS 63.4KB -> 2 blocks/CU, 512 >= 432 resident (spin-sync deadlock-free).

namespace {

constexpr int kNPT = 3280;
constexpr int kRS  = 72;   // subtree record stride: 64 beta + 8 pre-norm sums
constexpr int kAS  = 68;   // A row stride per (g,p)
constexpr unsigned kMAGIC  = 0x13579BDFu;
constexpr unsigned kMAGIC2 = 0x2468ACEFu;
__device__ __constant__ int LO[6] = {0, 1, 4, 13, 40, 121};
__device__ __constant__ int P3[5] = {1, 3, 9, 27, 81};

#define AGENT_LD(p)    __hip_atomic_load((p), __ATOMIC_RELAXED, __HIP_MEMORY_SCOPE_AGENT)
#define AGENT_ST(p, v) __hip_atomic_store((p), (v), __ATOMIC_RELAXED, __HIP_MEMORY_SCOPE_AGENT)

__device__ __forceinline__ void leaf_beta(const float* __restrict__ sPi,
                                          const float* __restrict__ pBm,
                                          int p, int xv, int g, float* b)
{
    float s = 0.f;
    #pragma unroll
    for (int c = 0; c < 8; ++c) {
        b[c] = sPi[(c * 3 + p) * 8 + g] * pBm[xv * 64 + c * 8 + g];
        s += b[c];
    }
    float ig = __builtin_amdgcn_rcpf(s);
    #pragma unroll
    for (int c = 0; c < 8; ++c) b[c] *= ig;
}

// acc[i] += (spg*bj[j]) * A[i][j] over j; A row via 2x b128 per j
__device__ __forceinline__ void matvec_acc(const float* __restrict__ arow,
                                           const float* __restrict__ bj,
                                           float spg, float* acc)
{
    #pragma unroll
    for (int j = 0; j < 8; ++j) {
        float4 a0 = *(const float4*)(arow + j * 8);
        float4 a1 = *(const float4*)(arow + j * 8 + 4);
        float cjv = spg * bj[j];
        acc[0] = fmaf(a0.x, cjv, acc[0]); acc[1] = fmaf(a0.y, cjv, acc[1]);
        acc[2] = fmaf(a0.z, cjv, acc[2]); acc[3] = fmaf(a0.w, cjv, acc[3]);
        acc[4] = fmaf(a1.x, cjv, acc[4]); acc[5] = fmaf(a1.y, cjv, acc[5]);
        acc[6] = fmaf(a1.z, cjv, acc[6]); acc[7] = fmaf(a1.w, cjv, acc[7]);
    }
}

__global__ __launch_bounds__(256, 2)
void fused(const float* __restrict__ lamA, const float* __restrict__ lamB,
           const float* __restrict__ lamPi, const float* __restrict__ lamSP,
           const int* __restrict__ x, float* __restrict__ out,
           unsigned* __restrict__ sy, float* __restrict__ bmG,
           float* __restrict__ b3, float* __restrict__ e3)
{
    const int tid = threadIdx.x, w = tid >> 6, lane = tid & 63;
    const int n = lane >> 3, g = lane & 7;
    __shared__ __align__(16) float sAg[24 * kAS];   // A    [g][p][j][i]
    __shared__ __align__(16) float sLAg[24 * kAS];  // AlogA same layout
    __shared__ float sPi[192], sLPi[192], sSP[24], sLSP[24];
    __shared__ float bW[4][40 * kRS];               // per-subtree records
    __shared__ __half bMidH[13 * 64];               // mid beta, fp16
    __shared__ float sMs[13 * 8];                   // mid pre-norm sums
    __shared__ unsigned char xW[4][124];
    unsigned* trCnt = sy + 32;
    unsigned* trFlg = sy + 2080;

    // ---- init gate ----
    if (tid == 0) {
        if (blockIdx.x == 0) {
            for (int i = 0; i < 64; ++i) AGENT_ST(&trCnt[i * 32], 0u);
            __builtin_amdgcn_s_waitcnt(0);
            AGENT_ST(&sy[0], kMAGIC);
        }
        unsigned long sp = 0;
        while (AGENT_LD(&sy[0]) != kMAGIC) {
            if (++sp > (1UL << 24)) break;
            __builtin_amdgcn_s_sleep(2);
        }
    }
    __syncthreads();

    // ================= phase 0: parameters =================
    if (blockIdx.x == 0) {   // Bm softmax -> bmG (transposed [m][c][g]) + flag
        float* rr = &bW[0][0];
        int row = tid >> 2, part = tid & 3;
        int c = row >> 3, gg = row & 7, m0 = part * 32;
        float mx = -1e30f;
        for (int mm = 0; mm < 32; ++mm)
            mx = fmaxf(mx, lamB[(c * 128 + m0 + mm) * 8 + gg]);
        rr[tid] = mx;
        __syncthreads();
        float m4 = fmaxf(fmaxf(rr[row * 4], rr[row * 4 + 1]),
                         fmaxf(rr[row * 4 + 2], rr[row * 4 + 3]));
        float s = 0.f;
        for (int mm = 0; mm < 32; ++mm)
            s += expf(lamB[(c * 128 + m0 + mm) * 8 + gg] - m4);
        rr[256 + tid] = s;
        __syncthreads();
        float stot = rr[256 + row * 4] + rr[256 + row * 4 + 1]
                   + rr[256 + row * 4 + 2] + rr[256 + row * 4 + 3];
        float inv = 1.f / stot;
        for (int mm = 0; mm < 32; ++mm)
            AGENT_ST(&bmG[(m0 + mm) * 64 + c * 8 + gg],
                     expf(lamB[(c * 128 + m0 + mm) * 8 + gg] - m4) * inv);
        __syncthreads();
        if (tid == 0) AGENT_ST(&sy[4], kMAGIC2);
    }
    for (int col = tid; col < 192; col += 256) {   // A softmax over i -> g-major
        int j = col / 24; int rem = col - j * 24; int p = rem >> 3; int gg = rem & 7;
        float v[8]; float mx = -1e30f;
        #pragma unroll
        for (int i = 0; i < 8; ++i) {
            v[i] = lamA[((i * 8 + j) * 3 + p) * 8 + gg];
            mx = fmaxf(mx, v[i]);
        }
        float s = 0.f;
        #pragma unroll
        for (int i = 0; i < 8; ++i) { v[i] = expf(v[i] - mx); s += v[i]; }
        float inv = 1.f / s;
        int base = (gg * 3 + p) * kAS + j * 8;
        #pragma unroll
        for (int i = 0; i < 8; ++i) {
            float sm = v[i] * inv;
            sAg[base + i]  = sm;
            sLAg[base + i] = sm * logf(sm);
        }
    }
    for (int col = tid; col < 24; col += 256) {    // Pi softmax over c
        int p = col >> 3; int gg = col & 7;
        float v[8]; float mx = -1e30f;
        #pragma unroll
        for (int c = 0; c < 8; ++c) {
            v[c] = lamPi[(c * 3 + p) * 8 + gg];
            mx = fmaxf(mx, v[c]);
        }
        float s = 0.f;
        #pragma unroll
        for (int c = 0; c < 8; ++c) { v[c] = expf(v[c] - mx); s += v[c]; }
        float inv = 1.f / s;
        #pragma unroll
        for (int c = 0; c < 8; ++c) {
            int idx = (c * 3 + p) * 8 + gg;
            float sm = v[c] * inv;
            sPi[idx]  = sm;
            sLPi[idx] = logf(sm);
        }
    }
    if (tid < 8) {                                 // SP softmax over p
        int gg = tid;
        float v0 = lamSP[gg], v1 = lamSP[8 + gg], v2 = lamSP[16 + gg];
        float mx = fmaxf(v0, fmaxf(v1, v2));
        float e0 = expf(v0 - mx), e1 = expf(v1 - mx), e2 = expf(v2 - mx);
        float inv = 1.f / (e0 + e1 + e2);
        sSP[gg] = e0 * inv; sSP[8 + gg] = e1 * inv; sSP[16 + gg] = e2 * inv;
        sLSP[gg] = logf(e0 * inv); sLSP[8 + gg] = logf(e1 * inv); sLSP[16 + gg] = logf(e2 * inv);
    }
    if (tid == 0) {        // Bm gate: one fence per block per launch
        unsigned long sp = 0;
        while (AGENT_LD(&sy[4]) != kMAGIC2) {
            if (++sp > (1UL << 24)) break;
            __builtin_amdgcn_s_sleep(2);
        }
        __threadfence();
    }
    __syncthreads();

    const float* pBm = bmG;
    const int id = blockIdx.x * 4 + w, t = id / 27, q = id % 27, xb = t * kNPT;
    float* bw = &bW[w][0];
    unsigned char* xw = &xW[w][0];

    // ================= phase 1: subtree up-pass =================
    for (int u = lane; u < 121; u += 64) {
        int gx;
        if (u == 0)       gx = 13 + q;
        else if (u < 4)   gx = 40  + q * 3  + (u - 1);
        else if (u < 13)  gx = 121 + q * 9  + (u - 4);
        else if (u < 40)  gx = 364 + q * 27 + (u - 13);
        else              gx = 1093 + q * 81 + (u - 40);
        xw[u] = (unsigned char)x[xb + gx];
    }
    __builtin_amdgcn_wave_barrier();

    for (int e = 3; e >= 0; --e) {
        int cnt = P3[e];
        for (int base = 0; base < cnt; base += 8) {
            int node = base + n;
            if (node < cnt) {
                float acc[8];
                #pragma unroll
                for (int i = 0; i < 8; ++i) acc[i] = 0.f;
                #pragma unroll
                for (int k = 0; k < 3; ++k) {
                    float bj[8];
                    if (e == 3) {
                        leaf_beta(sPi, pBm, k, xw[40 + 3 * node + k], g, bj);
                    } else {
                        int co = (LO[e + 1] + 3 * node + k) * kRS + g;
                        #pragma unroll
                        for (int j = 0; j < 8; ++j) bj[j] = bw[co + j * 8];
                    }
                    matvec_acc(&sAg[(g * 3 + k) * kAS], bj, sSP[k * 8 + g], acc);
                }
                if (e == 0) {
                    #pragma unroll
                    for (int i = 0; i < 8; ++i) bw[i * 8 + g] = acc[i];  // raw tb root
                    int xv = xw[0];
                    float s = 0.f;
                    #pragma unroll
                    for (int i = 0; i < 8; ++i) { acc[i] *= pBm[xv * 64 + i * 8 + g]; s += acc[i]; }
                    float ig = __builtin_amdgcn_rcpf(s);
                    #pragma unroll
                    for (int i = 0; i < 8; ++i)
                        AGENT_ST(&b3[id * 64 + i * 8 + g], acc[i] * ig);
                } else {
                    int slot = LO[e] + node;
                    int xv = xw[slot];
                    float s = 0.f;
                    #pragma unroll
                    for (int i = 0; i < 8; ++i) { acc[i] *= pBm[xv * 64 + i * 8 + g]; s += acc[i]; }
                    float ig = __builtin_amdgcn_rcpf(s);
                    int bo = slot * kRS + g;
                    #pragma unroll
                    for (int i = 0; i < 8; ++i) bw[bo + i * 8] = acc[i] * ig;
                    bw[slot * kRS + 64 + g] = s;
                }
            }
        }
        __builtin_amdgcn_wave_barrier();
    }
    __builtin_amdgcn_s_waitcnt(0);
    if (lane == 0)
        __hip_atomic_fetch_add(&trCnt[t * 32], 1u, __ATOMIC_RELAXED,
                               __HIP_MEMORY_SCOPE_AGENT);

    // ================= phase 2: mid (levels 0-3), q==0 wave per tree =========
    if (q == 0) {
        unsigned long sp = 0;
        while (AGENT_LD(&trCnt[t * 32]) < 27u) {
            if (++sp > (1UL << 22)) break;
            __builtin_amdgcn_s_sleep(1);
        }
        __threadfence();   // one invalidate; b3 then read via cached loads
        float ellm = 0.f;
        for (int f = 2; f >= 0; --f) {
            int cnt = (f == 2) ? 9 : (f == 1 ? 3 : 1);
            int pl0 = (f == 2) ? 4 : (f == 1 ? 1 : 0);
            int cl0 = (f == 1) ? 4 : 1;
            for (int base = 0; base < cnt; base += 8) {
                int pi = base + n;
                if (pi < cnt) {
                    float acc[8];
                    #pragma unroll
                    for (int i = 0; i < 8; ++i) acc[i] = 0.f;
                    #pragma unroll
                    for (int k = 0; k < 3; ++k) {
                        float bj[8];
                        if (f == 2) {
                            const float* src = b3 + (t * 27 + 3 * pi + k) * 64 + g;
                            #pragma unroll
                            for (int j = 0; j < 8; ++j) bj[j] = src[j * 8];
                        } else {
                            int co = (cl0 + 3 * pi + k) * 64 + g;
                            #pragma unroll
                            for (int j = 0; j < 8; ++j)
                                bj[j] = __half2float(bMidH[co + j * 8]);
                        }
                        matvec_acc(&sAg[(g * 3 + k) * kAS], bj, sSP[k * 8 + g], acc);
                    }
                    int slot = pl0 + pi;
                    int xv = x[xb + slot];
                    float s = 0.f;
                    #pragma unroll
                    for (int i = 0; i < 8; ++i) { acc[i] *= pBm[xv * 64 + i * 8 + g]; s += acc[i]; }
                    float ig = __builtin_amdgcn_rcpf(s);
                    int bo = slot * 64 + g;
                    #pragma unroll
                    for (int i = 0; i < 8; ++i)
                        bMidH[bo + i * 8] = __float2half(acc[i] * ig);
                    sMs[slot * 8 + g] = s;
                }
            }
            __builtin_amdgcn_wave_barrier();
        }
        if (n == 0) {     // root: ell Bm term; slot0 := r = Bm/s
            int xv = x[xb];
            float invs = __builtin_amdgcn_rcpf(sMs[g]);
            #pragma unroll
            for (int c = 0; c < 8; ++c)
                ellm += __half2float(bMidH[c * 8 + g]) * pBm[xv * 64 + c * 8 + g];
            #pragma unroll
            for (int c = 0; c < 8; ++c)
                bMidH[c * 8 + g] = __float2half(pBm[xv * 64 + c * 8 + g] * invs);
        }
        __builtin_amdgcn_wave_barrier();
        for (int f = 1; f <= 3; ++f) {
            int cnt = (f == 1) ? 3 : (f == 2 ? 9 : 27);
            int cl0 = (f == 1) ? 1 : (f == 2 ? 4 : 13);
            int pl0 = (f == 1) ? 0 : (f == 2 ? 1 : 4);
            for (int base = 0; base < cnt; base += 8) {
                int ci = base + n;
                if (ci < cnt) {
                    int p = ci % 3;
                    int ps = (pl0 + ci / 3) * 64 + g;
                    float r[8];
                    #pragma unroll
                    for (int i = 0; i < 8; ++i) r[i] = __half2float(bMidH[ps + i * 8]);
                    float bj[8]; float sv = 0.f;
                    if (f == 3) {
                        const float* src = b3 + (t * 27 + ci) * 64 + g;
                        #pragma unroll
                        for (int j = 0; j < 8; ++j) bj[j] = src[j * 8];
                    } else {
                        int co = (cl0 + ci) * 64 + g;
                        #pragma unroll
                        for (int j = 0; j < 8; ++j) bj[j] = __half2float(bMidH[co + j * 8]);
                        sv = sMs[(cl0 + ci) * 8 + g];
                    }
                    float spg = sSP[p * 8 + g];
                    const float* arow = &sAg[(g * 3 + p) * kAS];
                    const float* lrow = &sLAg[(g * 3 + p) * kAS];
                    float esum = 0.f, lg = 0.f;
                    float ev[8];
                    #pragma unroll
                    for (int j = 0; j < 8; ++j) {
                        float4 a0 = *(const float4*)(arow + j * 8);
                        float4 a1 = *(const float4*)(arow + j * 8 + 4);
                        float4 l0 = *(const float4*)(lrow + j * 8);
                        float4 l1 = *(const float4*)(lrow + j * 8 + 4);
                        float s1 = r[0] * a0.x; s1 = fmaf(r[1], a0.y, s1);
                        s1 = fmaf(r[2], a0.z, s1); s1 = fmaf(r[3], a0.w, s1);
                        s1 = fmaf(r[4], a1.x, s1); s1 = fmaf(r[5], a1.y, s1);
                        s1 = fmaf(r[6], a1.z, s1); s1 = fmaf(r[7], a1.w, s1);
                        float s2 = r[0] * l0.x; s2 = fmaf(r[1], l0.y, s2);
                        s2 = fmaf(r[2], l0.z, s2); s2 = fmaf(r[3], l0.w, s2);
                        s2 = fmaf(r[4], l1.x, s2); s2 = fmaf(r[5], l1.y, s2);
                        s2 = fmaf(r[6], l1.z, s2); s2 = fmaf(r[7], l1.w, s2);
                        float bs = spg * bj[j];
                        ev[j] = bs * s1;
                        lg    = fmaf(bs, s2, lg);
                        esum += ev[j];
                    }
                    lg = fmaf(esum, sLSP[p * 8 + g], lg);
                    int xv = x[xb + cl0 + ci];
                    float Bmv[8];
                    #pragma unroll
                    for (int c = 0; c < 8; ++c) {
                        Bmv[c] = pBm[xv * 64 + c * 8 + g];
                        lg = fmaf(ev[c], Bmv[c], lg);
                    }
                    if (f == 3) {
                        #pragma unroll
                        for (int j = 0; j < 8; ++j)
                            AGENT_ST(&e3[(t * 27 + ci) * 64 + j * 8 + g], ev[j]);
                    } else {
                        int co = (cl0 + ci) * 64 + g;
                        #pragma unroll
                        for (int j = 0; j < 8; ++j)
                            bMidH[co + j * 8] = __float2half(
                                ev[j] * Bmv[j] * __builtin_amdgcn_rcpf(bj[j] * sv));
                    }
                    ellm += lg;
                }
            }
            __builtin_amdgcn_wave_barrier();
        }
        ellm += __shfl_xor(ellm, 8);
        ellm += __shfl_xor(ellm, 16);
        ellm += __shfl_xor(ellm, 32);
        if (n == 0) atomicAdd(&out[t * 8 + g], -ellm);
        __builtin_amdgcn_s_waitcnt(0);
        if (lane == 0) AGENT_ST(&trFlg[t * 32], kMAGIC2);
    }

    // ================= phase 3: subtree down-pass =================
    {
        unsigned long sp = 0;
        while (AGENT_LD(&trFlg[t * 32]) != kMAGIC2) {
            if (++sp > (1UL << 22)) break;
            __builtin_amdgcn_s_sleep(1);
        }
    }
    bw[lane] = AGENT_LD(&e3[id * 64 + lane]) * __builtin_amdgcn_rcpf(bw[lane]);
    __builtin_amdgcn_wave_barrier();

    float ell = 0.f;
    for (int e = 1; e <= 4; ++e) {
        int cnt = P3[e], pl0 = LO[e - 1];
        for (int base = 0; base < cnt; base += 8) {
            int ci = base + n;
            if (ci < cnt) {
                int p = ci % 3;
                int ps = (pl0 + ci / 3) * kRS + g;
                float r[8];
                #pragma unroll
                for (int i = 0; i < 8; ++i) r[i] = bw[ps + i * 8];
                float bj[8]; float sv = 0.f;
                int xv;
                if (e == 4) {
                    xv = xw[40 + ci];
                    leaf_beta(sPi, pBm, p, xv, g, bj);
                } else {
                    int slot = LO[e] + ci;
                    xv = xw[slot];
                    int co = slot * kRS + g;
                    #pragma unroll
                    for (int j = 0; j < 8; ++j) bj[j] = bw[co + j * 8];
                    sv = bw[slot * kRS + 64 + g];
                }
                float spg = sSP[p * 8 + g];
                const float* arow = &sAg[(g * 3 + p) * kAS];
                const float* lrow = &sLAg[(g * 3 + p) * kAS];
                float esum = 0.f, lg = 0.f;
                float ev[8];
                #pragma unroll
                for (int j = 0; j < 8; ++j) {
                    float4 a0 = *(const float4*)(arow + j * 8);
                    float4 a1 = *(const float4*)(arow + j * 8 + 4);
                    float4 l0 = *(const float4*)(lrow + j * 8);
                    float4 l1 = *(const float4*)(lrow + j * 8 + 4);
                    float s1 = r[0] * a0.x; s1 = fmaf(r[1], a0.y, s1);
                    s1 = fmaf(r[2], a0.z, s1); s1 = fmaf(r[3], a0.w, s1);
                    s1 = fmaf(r[4], a1.x, s1); s1 = fmaf(r[5], a1.y, s1);
                    s1 = fmaf(r[6], a1.z, s1); s1 = fmaf(r[7], a1.w, s1);
                    float s2 = r[0] * l0.x; s2 = fmaf(r[1], l0.y, s2);
                    s2 = fmaf(r[2], l0.z, s2); s2 = fmaf(r[3], l0.w, s2);
                    s2 = fmaf(r[4], l1.x, s2); s2 = fmaf(r[5], l1.y, s2);
                    s2 = fmaf(r[6], l1.z, s2); s2 = fmaf(r[7], l1.w, s2);
                    float bs = spg * bj[j];
                    ev[j] = bs * s1;
                    lg    = fmaf(bs, s2, lg);
                    esum += ev[j];
                }
                lg = fmaf(esum, sLSP[p * 8 + g], lg);
                float Bmv[8];
                #pragma unroll
                for (int c = 0; c < 8; ++c) {
                    Bmv[c] = pBm[xv * 64 + c * 8 + g];
                    lg = fmaf(ev[c], Bmv[c], lg);
                }
                if (e < 4) {
                    int slot = LO[e] + ci;
                    int co = slot * kRS + g;
                    #pragma unroll
                    for (int j = 0; j < 8; ++j)
                        bw[co + j * 8] = ev[j] * Bmv[j]
                            * __builtin_amdgcn_rcpf(bj[j] * sv);
                } else {
                    #pragma unroll
                    for (int c = 0; c < 8; ++c)
                        lg = fmaf(ev[c], sLPi[(c * 3 + p) * 8 + g], lg);
                }
                ell += lg;
            }
        }
        __builtin_amdgcn_wave_barrier();
    }

    ell += __shfl_xor(ell, 8);
    ell += __shfl_xor(ell, 16);
    ell += __shfl_xor(ell, 32);
    if (n == 0) atomicAdd(&out[t * 8 + g], -ell);
}

} // namespace

extern "C" void kernel_launch(void* const* d_in, const int* in_sizes, int n_in,
                              void* d_out, int out_size, void* d_ws, size_t ws_size,
                              hipStream_t stream) {
    const float* lamA  = (const float*)d_in[0];
    const float* lamB  = (const float*)d_in[1];
    const float* lamPi = (const float*)d_in[2];
    const float* lamSP = (const float*)d_in[3];
    const int*   x     = (const int*)d_in[4];
    float* out = (float*)d_out;
    unsigned* sy  = (unsigned*)d_ws;        // sync area (32 KB)
    float* bmG = (float*)d_ws + 8192;       // 8192 floats
    float* b3  = bmG + 8192;                // 1728*64
    float* e3  = b3 + 1728 * 64;            // 1728*64

    fused<<<dim3(432), dim3(256), 0, stream>>>(
        lamA, lamB, lamPi, lamSP, x, out, sy, bmG, b3, e3);
}